// Round 7
// baseline (105.247 us; speedup 1.0000x reference)
//
#include <hip/hip_runtime.h>
#include <math.h>

#define BATCH 4096
#define NODES 256
#define FDIM  128
#define HID   16

typedef __attribute__((ext_vector_type(8))) short short8;  // 8 bf16 (4 VGPRs)
typedef __attribute__((ext_vector_type(4))) float f32x4;   // MFMA C/D frag

// bf16 split: x ~= hi + lo (truncation); 3 MFMAs (hi*hi+hi*lo+lo*hi) ~= fp32.
__device__ __forceinline__ short bf_trunc(float x) {
    return (short)(__float_as_uint(x) >> 16);
}
__device__ __forceinline__ float bf_back(short s) {
    return __uint_as_float(((unsigned)(unsigned short)s) << 16);
}
__device__ __forceinline__ void split8(float4 v0, float4 v1,
                                       short8& hi, short8& lo) {
    float v[8] = {v0.x, v0.y, v0.z, v0.w, v1.x, v1.y, v1.z, v1.w};
    #pragma unroll
    for (int j = 0; j < 8; ++j) {
        const short h = bf_trunc(v[j]);
        hi[j] = h;
        lo[j] = bf_trunc(v[j] - bf_back(h));
    }
}

// One block per batch element b; 4 waves; wave w owns rows 64w..64w+63 as
// 4 M-tiles of 16. Per-block GEMM [256x128]x[128x16] via mfma_16x16x32_bf16,
// weights live in B-fragments (32 VGPRs, loaded once). concat trick:
// pre-act = x_row*Ab + x0*At. The x0*At term (c0) is computed AFTER the main
// loop with the same MFMA path on a broadcast-A (all rows = x0): every lane's
// acc0[0] = c0[col n] directly (D-layout col=lane&15). No LDS for c0, no
// barriers before/inside the main loop, cold x0 latency overlaps other blocks.
// MFMA 16x16x32 layouts: A/B idx=lane&15, k=(lane>>4)*8+j; D col=lane&15,
// row=(lane>>4)*4+reg (m89-verified).
__launch_bounds__(256, 2)   // empirical: VGPR cap = 256/min_waves = 128
__global__ void mta_kernel(const float* __restrict__ x,
                           const float* __restrict__ a1,
                           const float* __restrict__ a2,
                           const float* __restrict__ adj,
                           const int*  __restrict__ node_index,
                           const int*  __restrict__ type_index,
                           float* __restrict__ out) {
    const int b    = blockIdx.x;
    const int tid  = threadIdx.x;
    const int lane = tid & 63;
    const int w    = tid >> 6;
    const int n    = lane & 15;   // output column (h) / A row idx
    const int g    = lane >> 4;   // k-group (0..3)

    __shared__ float es[NODES];
    __shared__ float redm[4], reds[4];

    const int t  = __builtin_amdgcn_readfirstlane(type_index[b]);
    const int ni = __builtin_amdgcn_readfirstlane(node_index[0]);

    const float* At  = a1 + (size_t)t * (2 * FDIM * HID); // top    [FDIM][HID]
    const float* Ab  = At + FDIM * HID;                   // bottom [FDIM][HID]
    const float* a2t = a2 + t * HID;
    const float* xb  = x + (size_t)b * NODES * FDIM;

    // ---- weight B-fragments: lane supplies Ab[k][n], k = kt*32 + g*8 + j ----
    short8 whi[4], wlo[4];
    #pragma unroll
    for (int kt = 0; kt < 4; ++kt) {
        float wv[8];
        #pragma unroll
        for (int j = 0; j < 8; ++j)
            wv[j] = Ab[(kt * 32 + g * 8 + j) * HID + n];   // L2-hot, 8KB shared
        float4 w0 = {wv[0], wv[1], wv[2], wv[3]};
        float4 w1 = {wv[4], wv[5], wv[6], wv[7]};
        split8(w0, w1, whi[kt], wlo[kt]);
    }

    // ---- main GEMM: 4 K-tiles x 4 M-tiles, A straight from global ----
    const int rowbase = w * 64;
    f32x4 acc[4];
    #pragma unroll
    for (int mt = 0; mt < 4; ++mt) acc[mt] = (f32x4){0.f, 0.f, 0.f, 0.f};

    #pragma unroll
    for (int kt = 0; kt < 4; ++kt) {
        float4 ra[4][2];
        #pragma unroll
        for (int mt = 0; mt < 4; ++mt) {
            const float* p = xb + (size_t)(rowbase + mt * 16 + n) * FDIM
                           + kt * 32 + g * 8;
            ra[mt][0] = *(const float4*)p;
            ra[mt][1] = *(const float4*)(p + 4);
        }
        #pragma unroll
        for (int mt = 0; mt < 4; ++mt) {
            short8 ahi, alo;
            split8(ra[mt][0], ra[mt][1], ahi, alo);
            acc[mt] = __builtin_amdgcn_mfma_f32_16x16x32_bf16(ahi, whi[kt], acc[mt], 0, 0, 0);
            acc[mt] = __builtin_amdgcn_mfma_f32_16x16x32_bf16(ahi, wlo[kt], acc[mt], 0, 0, 0);
            acc[mt] = __builtin_amdgcn_mfma_f32_16x16x32_bf16(alo, whi[kt], acc[mt], 0, 0, 0);
        }
    }

    // ---- c0 via MFMA: broadcast-A = x0, B = At fragments ----
    const float* x0 = xb + (size_t)ni * FDIM;
    f32x4 acc0 = (f32x4){0.f, 0.f, 0.f, 0.f};
    #pragma unroll
    for (int kt = 0; kt < 4; ++kt) {
        const float* p0 = x0 + kt * 32 + g * 8;     // same 32B for 16 lanes
        short8 a0hi, a0lo;
        split8(*(const float4*)p0, *(const float4*)(p0 + 4), a0hi, a0lo);
        float tv[8];
        #pragma unroll
        for (int j = 0; j < 8; ++j)
            tv[j] = At[(kt * 32 + g * 8 + j) * HID + n];
        float4 t0 = {tv[0], tv[1], tv[2], tv[3]};
        float4 t1 = {tv[4], tv[5], tv[6], tv[7]};
        short8 thi, tlo;
        split8(t0, t1, thi, tlo);
        acc0 = __builtin_amdgcn_mfma_f32_16x16x32_bf16(a0hi, thi, acc0, 0, 0, 0);
        acc0 = __builtin_amdgcn_mfma_f32_16x16x32_bf16(a0hi, tlo, acc0, 0, 0, 0);
        acc0 = __builtin_amdgcn_mfma_f32_16x16x32_bf16(a0lo, thi, acc0, 0, 0, 0);
    }
    const float c0h = acc0[0];    // all rows identical -> reg 0 suffices

    // ---- epilogue: e[row] = lrelu( sum_h lrelu(acc+c0[h]) * a2[h] ) ----
    const float a2h = a2t[n];
    #pragma unroll
    for (int mt = 0; mt < 4; ++mt) {
        #pragma unroll
        for (int r = 0; r < 4; ++r) {
            float v = acc[mt][r] + c0h;
            v = (v > 0.f) ? v : 0.01f * v;
            float s = v * a2h;
            s += __shfl_xor(s, 1);
            s += __shfl_xor(s, 2);
            s += __shfl_xor(s, 4);
            s += __shfl_xor(s, 8);      // sum over 16 h-lanes
            float e = (s > 0.f) ? s : 0.01f * s;
            if (n == 0) es[rowbase + mt * 16 + g * 4 + r] = e;
        }
    }
    __syncthreads();

    // ---- masked softmax over 256 nodes ----
    const float ee  = es[tid];
    const float m   = adj[tid];
    float       val = (m > 0.f) ? ee : -INFINITY;

    float mx = val;
    #pragma unroll
    for (int off = 32; off; off >>= 1) mx = fmaxf(mx, __shfl_xor(mx, off));
    const int wid = tid >> 6;
    if ((tid & 63) == 0) redm[wid] = mx;
    __syncthreads();
    mx = fmaxf(fmaxf(redm[0], redm[1]), fmaxf(redm[2], redm[3]));

    float pr = (m > 0.f) ? __expf(ee - mx) : 0.f;
    float s = pr;
    #pragma unroll
    for (int off = 32; off; off >>= 1) s += __shfl_xor(s, off);
    if ((tid & 63) == 0) reds[wid] = s;
    __syncthreads();
    const float Z = reds[0] + reds[1] + reds[2] + reds[3];

    out[(size_t)b * NODES + tid] = pr / Z;
}

extern "C" void kernel_launch(void* const* d_in, const int* in_sizes, int n_in,
                              void* d_out, int out_size, void* d_ws, size_t ws_size,
                              hipStream_t stream) {
    const float* x   = (const float*)d_in[0];
    const float* a1  = (const float*)d_in[1];
    const float* a2  = (const float*)d_in[2];
    const float* adj = (const float*)d_in[3];
    const int*   ni  = (const int*)d_in[4];
    const int*   ti  = (const int*)d_in[5];
    float* out = (float*)d_out;

    mta_kernel<<<BATCH, NODES, 0, stream>>>(x, a1, a2, adj, ni, ti, out);
}